// Round 1
// baseline (42.653 us; speedup 1.0000x reference)
//
#include <hip/hip_runtime.h>

// Shapes (fixed by setup_inputs): B=1, S=128, D=256, H=8, HD=32
#define S_LEN 128
#define DM 256
#define NH 8
#define HD 32

// exp(-(a-b)^2/2) = exp2(-(a'-b')^2) with a' = a*sqrt(0.5*log2(e))
static constexpr float KSCALE     = 0.84932180028801904f;  // sqrt(0.7213475204444817)
static constexpr float INV_KSCALE = 1.17741002251547466f;  // 1/KSCALE
static constexpr float LOG2E      = 1.44269504088896340f;

// ---------------- Kernel 1: x = inp @ w_in^T + b_in, then LayerNorm over HD ----------------
// One block per sequence row s, 256 threads (one per output dim d).
__global__ __launch_bounds__(256) void k_proj_ln(
    const float* __restrict__ inp, const float* __restrict__ w_in,
    const float* __restrict__ b_in, const float* __restrict__ ln_g,
    const float* __restrict__ ln_b, float* __restrict__ xn)
{
  const int s = blockIdx.x;
  const int d = threadIdx.x;
  __shared__ float row[DM];
  row[d] = inp[s * DM + d];
  __syncthreads();

  const float4* w4 = reinterpret_cast<const float4*>(w_in + d * DM);
  float acc = b_in[d];
#pragma unroll 8
  for (int k4 = 0; k4 < DM / 4; ++k4) {
    float4 w = w4[k4];
    acc += row[4 * k4 + 0] * w.x + row[4 * k4 + 1] * w.y +
           row[4 * k4 + 2] * w.z + row[4 * k4 + 3] * w.w;
  }

  // LayerNorm over each 32-thread group (consecutive lanes within a wave64 half)
  float sum = acc;
#pragma unroll
  for (int m = 1; m <= 16; m <<= 1) sum += __shfl_xor(sum, m);
  float mu = sum * (1.0f / HD);
  float c = acc - mu;
  float ss = c * c;
#pragma unroll
  for (int m = 1; m <= 16; m <<= 1) ss += __shfl_xor(ss, m);
  float r = rsqrtf(ss * (1.0f / HD) + 1e-5f);

  const int e = d & (HD - 1);
  const int h = d >> 5;
  float y = c * r * ln_g[e] + ln_b[e];
  // store pre-scaled for the exp2 distance kernel; layout [h][s][e]
  xn[(h * S_LEN + s) * HD + e] = y * KSCALE;
}

// ---------------- Kernel 2: pairwise Gaussian kernel + softmax + PV ----------------
// One block per (s, h); 128 threads, thread t owns column t of the attention row.
__global__ __launch_bounds__(128) void k_attn(
    const float* __restrict__ xn, float* __restrict__ ah)
{
  const int s = blockIdx.x;
  const int h = blockIdx.y;
  const int t = threadIdx.x;  // 0..127

  __shared__ float xh[S_LEN][HD + 1];  // +1 pad: 2-way bank aliasing only (free)
  __shared__ float red[4];
  __shared__ float P[S_LEN];
  __shared__ float po[4][HD];

  const float* base = xn + h * S_LEN * HD;
  for (int i = t; i < S_LEN * HD; i += 128) xh[i >> 5][i & 31] = base[i];
  __syncthreads();

  float xt[HD], xs[HD];
#pragma unroll
  for (int f = 0; f < HD; ++f) xt[f] = xh[t][f];
#pragma unroll
  for (int e = 0; e < HD; ++e) xs[e] = xh[s][e];

  float a0 = 0.f, a1 = 0.f, a2 = 0.f, a3 = 0.f;
  for (int e = 0; e < HD; ++e) {
    const float a = xs[e];
#pragma unroll
    for (int f = 0; f < HD; f += 4) {
      float d0 = a - xt[f + 0]; a0 += __builtin_amdgcn_exp2f(-(d0 * d0));
      float d1 = a - xt[f + 1]; a1 += __builtin_amdgcn_exp2f(-(d1 * d1));
      float d2 = a - xt[f + 2]; a2 += __builtin_amdgcn_exp2f(-(d2 * d2));
      float d3 = a - xt[f + 3]; a3 += __builtin_amdgcn_exp2f(-(d3 * d3));
    }
  }
  const float av = (a0 + a1 + a2 + a3) * (1.0f / HD);

  // softmax over 128 threads (2 waves): wave shuffle reduce + LDS combine
  float m = av;
#pragma unroll
  for (int msk = 1; msk <= 32; msk <<= 1) m = fmaxf(m, __shfl_xor(m, msk));
  if ((t & 63) == 0) red[t >> 6] = m;
  __syncthreads();
  m = fmaxf(red[0], red[1]);

  float p = __builtin_amdgcn_exp2f((av - m) * LOG2E);
  float ssum = p;
#pragma unroll
  for (int msk = 1; msk <= 32; msk <<= 1) ssum += __shfl_xor(ssum, msk);
  if ((t & 63) == 0) red[2 + (t >> 6)] = ssum;
  __syncthreads();
  const float denom = red[2] + red[3];
  P[t] = p / denom;
  __syncthreads();

  // PV: out[e] = sum_t P[t] * xh[t][e]; 4 t-groups of 32, then combine
  const int e = t & 31, g = t >> 5;
  float o = 0.f;
#pragma unroll
  for (int i = 0; i < 32; ++i) {
    const int tt = g * 32 + i;
    o += P[tt] * xh[tt][e];
  }
  po[g][e] = o;
  __syncthreads();
  if (t < HD) {
    float out = (po[0][t] + po[1][t] + po[2][t] + po[3][t]) * INV_KSCALE;
    ah[(h * S_LEN + s) * HD + t] = out;
  }
}

// ---------------- Kernel 3: out = perm(ah) @ w_out^T + b_out ----------------
__global__ __launch_bounds__(256) void k_out(
    const float* __restrict__ ah, const float* __restrict__ w_out,
    const float* __restrict__ b_out, float* __restrict__ out)
{
  const int s = blockIdx.x;
  const int d = threadIdx.x;
  __shared__ float row[DM];
  const int h = d >> 5, e = d & 31;
  row[d] = ah[(h * S_LEN + s) * HD + e];
  __syncthreads();

  const float4* w4 = reinterpret_cast<const float4*>(w_out + d * DM);
  float acc = b_out[d];
#pragma unroll 8
  for (int k4 = 0; k4 < DM / 4; ++k4) {
    float4 w = w4[k4];
    acc += row[4 * k4 + 0] * w.x + row[4 * k4 + 1] * w.y +
           row[4 * k4 + 2] * w.z + row[4 * k4 + 3] * w.w;
  }
  out[s * DM + d] = acc;
}

extern "C" void kernel_launch(void* const* d_in, const int* in_sizes, int n_in,
                              void* d_out, int out_size, void* d_ws, size_t ws_size,
                              hipStream_t stream) {
  const float* inp   = (const float*)d_in[0];
  const float* w_in  = (const float*)d_in[1];
  const float* b_in  = (const float*)d_in[2];
  const float* ln_g  = (const float*)d_in[3];
  const float* ln_b  = (const float*)d_in[4];
  const float* w_out = (const float*)d_in[5];
  const float* b_out = (const float*)d_in[6];
  float* out = (float*)d_out;

  float* xn = (float*)d_ws;          // [NH][S][HD] scaled, 32768 floats
  float* ah = xn + S_LEN * DM;       // [NH][S][HD], 32768 floats

  k_proj_ln<<<S_LEN, DM, 0, stream>>>(inp, w_in, b_in, ln_g, ln_b, xn);
  k_attn<<<dim3(S_LEN, NH), 128, 0, stream>>>(xn, ah);
  k_out<<<S_LEN, DM, 0, stream>>>(ah, w_out, b_out, out);
}

// Round 2
// 40.028 us; speedup vs baseline: 1.0656x; 1.0656x over previous
//
#include <hip/hip_runtime.h>

// Shapes fixed by setup_inputs: B=1, S=128, D=256, H=8, HD=32
#define S_LEN 128
#define DM 256
#define NH 8
#define HD 32
#define NP 56   // Taylor/Mercer feature terms: exp(-(a-b)^2/2) = sum_n psi_n(a) psi_n(b)

static constexpr float LOG2E    = 1.44269504088896340f;
static constexpr float HLOG2E   = 0.72134752044448170f;  // log2(e)/2

// RS[n] = 1/sqrt(n), n=1..55 (RS[0] unused)
__device__ const float RS[NP] = {
  0.0f,        1.0f,        0.70710678f, 0.57735027f, 0.5f,        0.44721360f,
  0.40824829f, 0.37796447f, 0.35355339f, 0.33333333f, 0.31622777f, 0.30151134f,
  0.28867513f, 0.27735010f, 0.26726124f, 0.25819889f, 0.25f,       0.24253563f,
  0.23570226f, 0.22941573f, 0.22360680f, 0.21821789f, 0.21320072f, 0.20851441f,
  0.20412415f, 0.2f,        0.19611614f, 0.19245009f, 0.18898224f, 0.18569534f,
  0.18257419f, 0.17960530f, 0.17677670f, 0.17407766f, 0.17149859f, 0.16903085f,
  0.16666667f, 0.16439899f, 0.16222142f, 0.16012815f, 0.15811388f, 0.15617376f,
  0.15430335f, 0.15249857f, 0.15075567f, 0.14907120f, 0.14744196f, 0.14586499f,
  0.14433757f, 0.14285714f, 0.14142136f, 0.14002801f, 0.13867505f, 0.13736056f,
  0.13608276f, 0.13483997f
};

// ---------------- Kernel 1: proj + LayerNorm + Mercer features ----------------
// grid = 256 (s * 2 halves), block = 128. Each block: one s row, 128 output dims.
__global__ __launch_bounds__(128) void k_proj_ln_feat(
    const float* __restrict__ inp, const float* __restrict__ w_in,
    const float* __restrict__ b_in, const float* __restrict__ ln_g,
    const float* __restrict__ ln_b, float* __restrict__ xn,
    float* __restrict__ F, float* __restrict__ Fs)
{
  const int s     = blockIdx.x >> 1;
  const int half  = blockIdx.x & 1;
  const int dbase = half * 128;
  const int tid   = threadIdx.x;

  __shared__ float row[DM];
  __shared__ float xblk[128];

  row[tid]       = inp[s * DM + tid];
  row[tid + 128] = inp[s * DM + tid + 128];
  __syncthreads();

  // GEMV: 8 groups of 16 lanes; group g computes output d = dbase + p*8 + g.
  // Lane j reads w[d][k] coalesced (16 lanes x float4 = 256B contiguous).
  const int g = tid >> 4;
  const int j = tid & 15;
  const float4* rowv = reinterpret_cast<const float4*>(row);
  for (int p = 0; p < 16; ++p) {
    const int dl = p * 8 + g;
    const int d  = dbase + dl;
    const float4* w4 = reinterpret_cast<const float4*>(w_in + d * DM);
    float4 a4 = {0.f, 0.f, 0.f, 0.f};
#pragma unroll
    for (int c = 0; c < 4; ++c) {
      float4 w = w4[c * 16 + j];
      float4 r = rowv[c * 16 + j];
      a4.x += w.x * r.x; a4.y += w.y * r.y; a4.z += w.z * r.z; a4.w += w.w * r.w;
    }
    float acc = (a4.x + a4.y) + (a4.z + a4.w);
#pragma unroll
    for (int m = 1; m <= 8; m <<= 1) acc += __shfl_xor(acc, m);
    if (j == 0) xblk[dl] = acc + b_in[d];
  }
  __syncthreads();

  // LayerNorm over each 32-lane head group
  const float accd = xblk[tid];
  float sum = accd;
#pragma unroll
  for (int m = 1; m <= 16; m <<= 1) sum += __shfl_xor(sum, m);
  const float mu = sum * (1.0f / HD);
  const float c  = accd - mu;
  float ss = c * c;
#pragma unroll
  for (int m = 1; m <= 16; m <<= 1) ss += __shfl_xor(ss, m);
  const float r = rsqrtf(ss * (1.0f / HD) + 1e-5f);

  const int e = tid & 31;
  const int h = half * 4 + (tid >> 5);
  const float y = c * r * ln_g[e] + ln_b[e];
  xn[(h * S_LEN + s) * HD + e] = y;

  // Mercer features: psi_0 = exp(-y^2/2); psi_{n+1} = psi_n * y / sqrt(n+1)
  // U_n(h,s) = sum_e psi_n(y_e)  -> F[h][n][s] and Fs[s][h*NP+n]
  float psi = __builtin_amdgcn_exp2f(-HLOG2E * y * y);
  {
    float u = psi;
#pragma unroll
    for (int m = 1; m <= 16; m <<= 1) u += __shfl_xor(u, m);
    if (e == 0) { F[(h * NP) * S_LEN + s] = u; Fs[s * (NH * NP) + h * NP] = u; }
  }
  for (int n = 1; n < NP; ++n) {
    psi *= y * RS[n];
    float u = psi;
#pragma unroll
    for (int m = 1; m <= 16; m <<= 1) u += __shfl_xor(u, m);
    if (e == 0) { F[(h * NP + n) * S_LEN + s] = u; Fs[s * (NH * NP) + h * NP + n] = u; }
  }
}

// ---------------- Kernel 2: Gram attn + softmax + PV + out-projection ----------------
// grid = 128 (one block per s), block = 256.
__global__ __launch_bounds__(256) void k_attn_out(
    const float* __restrict__ xn, const float* __restrict__ F,
    const float* __restrict__ Fs, const float* __restrict__ w_out,
    const float* __restrict__ b_out, float* __restrict__ out)
{
  const int s   = blockIdx.x;
  const int tid = threadIdx.x;

  __shared__ float fsl[NH * NP];     // this row's features, all heads (448)
  __shared__ float Pl[NH][S_LEN];    // softmax probabilities
  __shared__ float ahrow[DM];        // attention output row, d = h*32+e order

  if (tid < 224) {
    fsl[tid]       = Fs[s * (NH * NP) + tid];
    fsl[tid + 224] = Fs[s * (NH * NP) + tid + 224];
  }
  __syncthreads();

  // ---- attn logits + softmax: 32-lane group per head; lane l owns t = 4l..4l+3
  {
    const int h = tid >> 5;
    const int l = tid & 31;
    const float4* Fh4 = reinterpret_cast<const float4*>(F + h * NP * S_LEN);
    const float*  fr  = fsl + h * NP;
    float4 acc = {0.f, 0.f, 0.f, 0.f};
#pragma unroll 8
    for (int n = 0; n < NP; ++n) {
      const float un = fr[n];
      float4 v = Fh4[n * 32 + l];
      acc.x += un * v.x; acc.y += un * v.y; acc.z += un * v.z; acc.w += un * v.w;
    }
    const float sc = 1.0f / HD;
    float r0 = acc.x * sc, r1 = acc.y * sc, r2 = acc.z * sc, r3 = acc.w * sc;
    float m = fmaxf(fmaxf(r0, r1), fmaxf(r2, r3));
#pragma unroll
    for (int msk = 1; msk <= 16; msk <<= 1) m = fmaxf(m, __shfl_xor(m, msk));
    float p0 = __builtin_amdgcn_exp2f((r0 - m) * LOG2E);
    float p1 = __builtin_amdgcn_exp2f((r1 - m) * LOG2E);
    float p2 = __builtin_amdgcn_exp2f((r2 - m) * LOG2E);
    float p3 = __builtin_amdgcn_exp2f((r3 - m) * LOG2E);
    float ps = (p0 + p1) + (p2 + p3);
#pragma unroll
    for (int msk = 1; msk <= 16; msk <<= 1) ps += __shfl_xor(ps, msk);
    const float inv = 1.0f / ps;
    float4 pv = {p0 * inv, p1 * inv, p2 * inv, p3 * inv};
    *reinterpret_cast<float4*>(&Pl[h][4 * l]) = pv;
  }
  __syncthreads();

  // ---- PV: group = head, lane = e; coalesced xn reads, broadcast P reads
  {
    const int h = tid >> 5;
    const int e = tid & 31;
    const float* xh = xn + h * S_LEN * HD + e;
    const float* Ph = Pl[h];
    float o = 0.f;
#pragma unroll 8
    for (int t = 0; t < S_LEN; ++t) o += Ph[t] * xh[t * HD];
    ahrow[h * HD + e] = o;
  }
  __syncthreads();

  // ---- out projection GEMV: 16 groups of 16 lanes, 16 passes
  const int g = tid >> 4;
  const int j = tid & 15;
  const float4* rowv = reinterpret_cast<const float4*>(ahrow);
  for (int p = 0; p < 16; ++p) {
    const int d = p * 16 + g;
    const float4* w4 = reinterpret_cast<const float4*>(w_out + d * DM);
    float4 a4 = {0.f, 0.f, 0.f, 0.f};
#pragma unroll
    for (int c = 0; c < 4; ++c) {
      float4 w = w4[c * 16 + j];
      float4 r = rowv[c * 16 + j];
      a4.x += w.x * r.x; a4.y += w.y * r.y; a4.z += w.z * r.z; a4.w += w.w * r.w;
    }
    float acc = (a4.x + a4.y) + (a4.z + a4.w);
#pragma unroll
    for (int m = 1; m <= 8; m <<= 1) acc += __shfl_xor(acc, m);
    if (j == 0) out[s * DM + d] = acc + b_out[d];
  }
}

extern "C" void kernel_launch(void* const* d_in, const int* in_sizes, int n_in,
                              void* d_out, int out_size, void* d_ws, size_t ws_size,
                              hipStream_t stream) {
  const float* inp   = (const float*)d_in[0];
  const float* w_in  = (const float*)d_in[1];
  const float* b_in  = (const float*)d_in[2];
  const float* ln_g  = (const float*)d_in[3];
  const float* ln_b  = (const float*)d_in[4];
  const float* w_out = (const float*)d_in[5];
  const float* b_out = (const float*)d_in[6];
  float* out = (float*)d_out;

  float* xn = (float*)d_ws;                    // [NH][S][HD]        32768 floats
  float* F  = xn + NH * S_LEN * HD;            // [NH][NP][S]        57344 floats
  float* Fs = F + NH * NP * S_LEN;             // [S][NH*NP]         57344 floats

  k_proj_ln_feat<<<2 * S_LEN, 128, 0, stream>>>(inp, w_in, b_in, ln_g, ln_b, xn, F, Fs);
  k_attn_out<<<S_LEN, 256, 0, stream>>>(xn, F, Fs, w_out, b_out, out);
}